// Round 12
// baseline (107.755 us; speedup 1.0000x reference)
//
#include <hip/hip_runtime.h>
#include <hip/hip_bf16.h>

#define NB 128
#define NT 1024
#define ND 512
#define NDA 576   // 512 (memory) + 64 (im2col window, 62 used + 2 zero pad)
#define NQ 1024
#define NA 128
#define NF 32
#define NK 31
#define CT3 32
#define NCH3 (NT / CT3)    // 32
#define NPAR 8             // persistent blocks per batch
#define ROWB 1152          // bytes per LDS sv row (576 bf16)

typedef __attribute__((ext_vector_type(8))) short short8;
typedef __attribute__((ext_vector_type(4))) float f32x4;
typedef __attribute__((ext_vector_type(4))) unsigned int u32x4;
typedef __attribute__((ext_vector_type(2))) unsigned int u32x2;

__device__ __forceinline__ unsigned short f2bf(float f) {
  unsigned int u = __float_as_uint(f);
  u += 0x7fffu + ((u >> 16) & 1u);   // RNE; inputs are finite
  return (unsigned short)(u >> 16);
}
__device__ __forceinline__ unsigned int cvt_pk_bf16(float lo, float hi) {
  unsigned int r;
  asm("v_cvt_pk_bf16_f32 %0, %1, %2" : "=v"(r) : "v"(lo), "v"(hi));
  return r;
}
__device__ __forceinline__ float bf2f(unsigned short u) {
  return __uint_as_float((unsigned int)u << 16);
}
__device__ __forceinline__ float fast_tanh(float x) {
  const float e = __expf(2.f * x);
  return 1.f - 2.f / (e + 1.f);
}
// wt3 packed layout: per (col-tile ct = a>>4, kf = d>>5) a 1KB block,
// lane (lhi = (d>>3)&3, llo = a&15) holds 8 bf16 along k.
__device__ __forceinline__ int wt3_off(int a, int d) {
  return (((a >> 4) * 18 + (d >> 5)) << 9) + (((d >> 3) & 3) << 7) +
         ((a & 15) << 3) + (d & 7);
}

// ---------------------------------------------------------------------------
// Prep: pq partials (0..511), Wm^T -> wt3 (512..575), W2 = ck@Wloc (576..583)
// ---------------------------------------------------------------------------
__global__ __launch_bounds__(256) void lsa_prep(
    const float* __restrict__ query, const float* __restrict__ wq,
    const float* __restrict__ wm, const float* __restrict__ ck,
    const float* __restrict__ wloc,
    float* __restrict__ pq_part, unsigned short* __restrict__ wt3)
{
  const int bid = blockIdx.x;
  const int tid = threadIdx.x;
  if (bid < 512) {
    __shared__ float qs[256];
    __shared__ float red[256];
    const int b = bid >> 2;
    const int qg = bid & 3;
    qs[tid] = query[(size_t)b * NQ + qg * 256 + tid];
    __syncthreads();
    const int a = tid & 127;
    const int h = tid >> 7;
    const float* wqp = wq + (size_t)(qg * 256 + h * 128) * NA + a;
    float acc = 0.f;
#pragma unroll 8
    for (int qi = 0; qi < 128; ++qi)
      acc += qs[h * 128 + qi] * wqp[(size_t)qi * NA];
    red[tid] = acc;
    __syncthreads();
    if (h == 0) pq_part[((size_t)b * 4 + qg) * NA + a] = red[a] + red[128 + a];
  } else if (bid < 576) {
    const int blk = bid - 512;   // 0..63, 8 d-rows each
    for (int i = blk * 1024 + tid; i < blk * 1024 + 1024; i += 256) {
      const int dd = i >> 7, aa = i & 127;
      wt3[wt3_off(aa, dd)] = f2bf(wm[(size_t)dd * NA + aa]);
    }
  } else {
    // W2[w][a] = sum_f ck[k][ch][f]*wloc[f][a], w = 2k+ch; w=62,63 -> 0
    __shared__ float wl_s[NF * NA];
    __shared__ float ck_s[NK * 2 * NF];
    const int blk = bid - 576;   // 0..7
    for (int i = tid; i < NF * NA; i += 256) wl_s[i] = wloc[i];
    for (int i = tid; i < NK * 2 * NF; i += 256) ck_s[i] = ck[i];
    __syncthreads();
    const int a = tid & 127;
    const int h = tid >> 7;
#pragma unroll
    for (int wi = 0; wi < 4; ++wi) {
      const int w = blk * 8 + h * 4 + wi;
      float acc = 0.f;
      if (w < 62) {
        const int k = w >> 1, ch = w & 1;
#pragma unroll
        for (int f = 0; f < NF; ++f)
          acc += ck_s[k * 64 + ch * 32 + f] * wl_s[f * NA + a];
      }
      wt3[wt3_off(a, 512 + w)] = f2bf(acc);
    }
  }
}

// ---------------------------------------------------------------------------
// Main: persistent (b, par) blocks, 8 waves, chunks ci = par + 8j.
// B (18 frags / 16 cols per wave) loaded ONCE into named registers.
// Per chunk: stage -> GEMM -> exp (no max) -> partial context. 3 barriers.
// ---------------------------------------------------------------------------
#define BDECL(K) const short8 bq##K = *(const short8*)(bbase + (K) * 512);

#define GSTEP(K) { \
  const int bo = ((K) * 64 + lhi * 16) ^ asw; \
  const short8 a0 = *(const short8*)(ab0 + bo); \
  const short8 a1 = *(const short8*)(ab1 + bo); \
  acc0 = __builtin_amdgcn_mfma_f32_16x16x32_bf16(a0, bq##K, acc0, 0, 0, 0); \
  acc1 = __builtin_amdgcn_mfma_f32_16x16x32_bf16(a1, bq##K, acc1, 0, 0, 0); }

__global__ __launch_bounds__(512, 4) void lsa_main(
    const float* __restrict__ memory, const int* __restrict__ msl,
    const float* __restrict__ prev, const float* __restrict__ cum,
    const float* __restrict__ pq_part, const float* __restrict__ v_g,
    const unsigned short* __restrict__ wt3,
    float* __restrict__ score_g, float* __restrict__ pl_g,
    float* __restrict__ pctx_g)
{
  const int bid = blockIdx.x;
  const int b = bid >> 3;
  const int par = bid & 7;
  const int len = msl[b];
  const int ncv = (len + 31) >> 5;             // 16..32 valid chunks
  if (par >= ncv) return;
  const int nk = (ncv - par + 7) >> 3;         // 2..4 chunks for this block
  const int tid = threadIdx.x;
  const int wid = tid >> 6;                    // 0..7
  const int lane = tid & 63;
  const int llo = lane & 15, lhi = lane >> 4;

  __shared__ __align__(16) unsigned short sv[CT3 * NDA];  // 36 KB
  __shared__ float score2[8][CT3];

  // ---- prologue: B into 18 named regs (this wave's 16 cols), pq/v ----
  const unsigned short* bbase = wt3 + ((size_t)wid * 18) * 512 + lane * 8;
  BDECL(0)  BDECL(1)  BDECL(2)  BDECL(3)  BDECL(4)  BDECL(5)
  BDECL(6)  BDECL(7)  BDECL(8)  BDECL(9)  BDECL(10) BDECL(11)
  BDECL(12) BDECL(13) BDECL(14) BDECL(15) BDECL(16) BDECL(17)
  const int c = wid * 16 + llo;                // this lane's output column
  const float* pp = pq_part + (size_t)b * 4 * NA;
  const float pqc = pp[c] + pp[NA + c] + pp[2 * NA + c] + pp[3 * NA + c];
  const float vc = v_g[c];

  const char* ab0 = (const char*)sv + llo * ROWB;          // rows 0..15
  const char* ab1 = (const char*)sv + (llo + 16) * ROWB;   // rows 16..31
  const int asw = (llo & 7) << 4;

  // ---------------- chunk loop ----------------
  for (int j = 0; j < nk; ++j) {
    const int ci = par + 8 * j;
    const int t0 = ci * CT3;
    const int nvalid = min(CT3, len - t0);

    // ---- stage values -> bf16 LDS (swizzled); 32 floats per thread ----
    {
      const int r = tid >> 4;          // 0..31
      const int jj = tid & 15;
      const float* src = memory + ((size_t)b * NT + (t0 + r)) * ND + jj * 8;
      const f32x4 y0 = *(const f32x4*)(src);
      const f32x4 y1 = *(const f32x4*)(src + 4);
      const f32x4 y2 = *(const f32x4*)(src + 128);
      const f32x4 y3 = *(const f32x4*)(src + 132);
      const f32x4 y4 = *(const f32x4*)(src + 256);
      const f32x4 y5 = *(const f32x4*)(src + 260);
      const f32x4 y6 = *(const f32x4*)(src + 384);
      const f32x4 y7 = *(const f32x4*)(src + 388);
      char* svb = (char*)sv + r * ROWB;
      const int sw = (r & 7) << 4;
      u32x4 pk;
      pk[0] = cvt_pk_bf16(y0[0], y0[1]); pk[1] = cvt_pk_bf16(y0[2], y0[3]);
      pk[2] = cvt_pk_bf16(y1[0], y1[1]); pk[3] = cvt_pk_bf16(y1[2], y1[3]);
      *(u32x4*)(svb + ((jj * 16) ^ sw)) = pk;
      pk[0] = cvt_pk_bf16(y2[0], y2[1]); pk[1] = cvt_pk_bf16(y2[2], y2[3]);
      pk[2] = cvt_pk_bf16(y3[0], y3[1]); pk[3] = cvt_pk_bf16(y3[2], y3[3]);
      *(u32x4*)(svb + ((jj * 16 + 256) ^ sw)) = pk;
      pk[0] = cvt_pk_bf16(y4[0], y4[1]); pk[1] = cvt_pk_bf16(y4[2], y4[3]);
      pk[2] = cvt_pk_bf16(y5[0], y5[1]); pk[3] = cvt_pk_bf16(y5[2], y5[3]);
      *(u32x4*)(svb + ((jj * 16 + 512) ^ sw)) = pk;
      pk[0] = cvt_pk_bf16(y6[0], y6[1]); pk[1] = cvt_pk_bf16(y6[2], y6[3]);
      pk[2] = cvt_pk_bf16(y7[0], y7[1]); pk[3] = cvt_pk_bf16(y7[2], y7[3]);
      *(u32x4*)(svb + ((jj * 16 + 768) ^ sw)) = pk;
    }
    // ---- im2col window into cols 512..575 (4 w's per thread) ----
    {
      const int t = tid >> 4;
      const int w0 = (tid & 15) * 4;
      float xv[4];
#pragma unroll
      for (int i = 0; i < 4; ++i) {
        const int w = w0 + i;
        xv[i] = 0.f;
        if (w < 62) {
          const int t3 = t0 - 15 + (w >> 1) + t;
          if (t3 >= 0 && t3 < NT)
            xv[i] = (w & 1) ? cum[(size_t)b * NT + t3] : prev[(size_t)b * NT + t3];
        }
      }
      u32x2 pk;
      pk[0] = cvt_pk_bf16(xv[0], xv[1]);
      pk[1] = cvt_pk_bf16(xv[2], xv[3]);
      *(u32x2*)((char*)sv + t * ROWB + ((1024 + w0 * 2) ^ ((t & 7) << 4))) = pk;
    }
    __syncthreads();   // bar1: sv ready

    // ---- GEMM: 32(t) x 16 cols/wave x 576(k); B from registers ----
    {
      f32x4 acc0 = {0.f, 0.f, 0.f, 0.f};
      f32x4 acc1 = {0.f, 0.f, 0.f, 0.f};
      GSTEP(0)  GSTEP(1)  GSTEP(2)  GSTEP(3)  GSTEP(4)  GSTEP(5)
      GSTEP(6)  GSTEP(7)  GSTEP(8)  GSTEP(9)  GSTEP(10) GSTEP(11)
      GSTEP(12) GSTEP(13) GSTEP(14) GSTEP(15) GSTEP(16) GSTEP(17)
#pragma unroll
      for (int mf = 0; mf < 2; ++mf) {
        const f32x4 av = mf ? acc1 : acc0;
#pragma unroll
        for (int rg = 0; rg < 4; ++rg) {
          const int r = mf * 16 + lhi * 4 + rg;
          float e = fast_tanh(av[rg] + pqc) * vc;
          e += __shfl_xor(e, 1); e += __shfl_xor(e, 2);
          e += __shfl_xor(e, 4); e += __shfl_xor(e, 8);
          if (llo == 0) score2[wid][r] = e;
        }
      }
    }
    __syncthreads();   // bar2: score2 ready

    // ---- exp weights (no max; |s| <= sum|v| ~ 9, f32-safe) ----
    float esc;
    {
      const int t = lane & 31;
      float s = 0.f;
#pragma unroll
      for (int w = 0; w < 8; ++w) s += score2[w][t];
      if (wid == 0 && lane < CT3) score_g[(size_t)b * NT + t0 + t] = s;
      esc = (t < nvalid) ? __expf(s) : 0.f;
      float l = esc;
      l += __shfl_xor(l, 1);  l += __shfl_xor(l, 2);  l += __shfl_xor(l, 4);
      l += __shfl_xor(l, 8);  l += __shfl_xor(l, 16);
      if (wid == 0 && lane == 0) pl_g[b * NCH3 + ci] = l;
    }

    // ---- partial context: wave covers 64 d's (8 groups of 8) ----
    {
      const int gi = lane >> 3;          // 0..7
      const int sub = lane & 7;          // t-part
      const int g = wid * 8 + gi;        // d-group, d0 = 8g
      const char* svb = (const char*)sv;
      float a8[8];
#pragma unroll
      for (int i = 0; i < 8; ++i) a8[i] = 0.f;
#pragma unroll
      for (int tp = 0; tp < 4; ++tp) {
        const int t2 = tp * 8 + sub;
        const float ee = __shfl(esc, t2);  // lane t2 holds esc for row t2
        const short8 u =
            *(const short8*)(svb + t2 * ROWB + ((g * 16) ^ ((t2 & 7) << 4)));
#pragma unroll
        for (int i = 0; i < 8; ++i) a8[i] += ee * bf2f((unsigned short)u[i]);
      }
#pragma unroll
      for (int off = 1; off < 8; off <<= 1) {
#pragma unroll
        for (int i = 0; i < 8; ++i) a8[i] += __shfl_xor(a8[i], off);
      }
      if (sub == 0) {
        float* dst = pctx_g + ((size_t)(b * NCH3 + ci)) * ND + g * 8;
        const f32x4 lo = {a8[0], a8[1], a8[2], a8[3]};
        const f32x4 hi = {a8[4], a8[5], a8[6], a8[7]};
        *(f32x4*)dst = lo;
        *(f32x4*)(dst + 4) = hi;
      }
    }
    __syncthreads();   // bar3: sv/score2 reads done; next stage may overwrite
  }
}

// ---------------------------------------------------------------------------
// Combine: merge <=32 chunk partials per batch (no rescale: same exp scale).
// Grid NB*2: block (b, half) does 256 d's and 512 t's.
// ---------------------------------------------------------------------------
__global__ __launch_bounds__(256) void lsa_comb(
    const int* __restrict__ msl, const float* __restrict__ score_g,
    const float* __restrict__ cum, const float* __restrict__ pl_g,
    const float* __restrict__ pctx_g, float* __restrict__ out)
{
  const int bid = blockIdx.x;
  const int b = bid >> 1;
  const int hf = bid & 1;
  const int tid = threadIdx.x;
  const int len = msl[b];
  const int nck = (len + CT3 - 1) >> 5;   // 16..32
  __shared__ float MLsh;
  if (tid < 64) {
    float L = (tid < nck) ? pl_g[b * NCH3 + tid] : 0.f;
#pragma unroll
    for (int off = 1; off < 32; off <<= 1) L += __shfl_xor(L, off);
    if (tid == 0) MLsh = L;
  }
  __syncthreads();
  const float Linv = 1.f / MLsh;
  {
    const int d = hf * 256 + tid;
    const float* pb = pctx_g + (size_t)b * NCH3 * ND + d;
    float a0 = 0.f, a1 = 0.f, a2 = 0.f, a3 = 0.f;
    int i = 0;
    for (; i + 4 <= nck; i += 4) {
      a0 += pb[(size_t)(i + 0) * ND];
      a1 += pb[(size_t)(i + 1) * ND];
      a2 += pb[(size_t)(i + 2) * ND];
      a3 += pb[(size_t)(i + 3) * ND];
    }
    for (; i < nck; ++i) a0 += pb[(size_t)i * ND];
    out[(size_t)b * ND + d] = (a0 + a1 + a2 + a3) * Linv;
  }
  float* attn_o = out + (size_t)NB * ND;
  float* cum_o = attn_o + (size_t)NB * NT;
#pragma unroll
  for (int it = 0; it < 2; ++it) {
    const int t = hf * 512 + it * 256 + tid;
    float w = 0.f;
    if (t < len) w = __expf(score_g[(size_t)b * NT + t]) * Linv;
    attn_o[(size_t)b * NT + t] = w;
    cum_o[(size_t)b * NT + t] = w + cum[(size_t)b * NT + t];
  }
}

extern "C" void kernel_launch(void* const* d_in, const int* in_sizes, int n_in,
                              void* d_out, int out_size, void* d_ws, size_t ws_size,
                              hipStream_t stream) {
  const float* query  = (const float*)d_in[0];
  const float* prev   = (const float*)d_in[1];
  const float* cum    = (const float*)d_in[2];
  const float* memory = (const float*)d_in[3];
  const int*   msl    = (const int*)d_in[4];
  const float* wq     = (const float*)d_in[5];
  const float* wm     = (const float*)d_in[6];
  const float* ck     = (const float*)d_in[7];
  const float* wloc   = (const float*)d_in[8];
  const float* vv     = (const float*)d_in[9];
  float* out = (float*)d_out;

  // workspace layout (floats), ~9.5 MB
  float* ws = (float*)d_ws;
  float* score_g = ws;                        // 131072
  float* pl_g    = ws + 131072;               // 4096
  float* pctx_g  = ws + 135168;               // 128*32*512 = 2097152
  float* pq_part = ws + 2232320;              // 65536
  unsigned short* wt3 = (unsigned short*)(ws + 2297856);  // 73728 bf16

  lsa_prep<<<584, 256, 0, stream>>>(query, wq, wm, ck, wloc, pq_part, wt3);
  lsa_main<<<NB * NPAR, 512, 0, stream>>>(memory, msl, prev, cum, pq_part, vv,
                                          wt3, score_g, pl_g, pctx_g);
  lsa_comb<<<NB * 2, 256, 0, stream>>>(msl, score_g, cum, pl_g, pctx_g, out);
}

// Round 13
// 79.790 us; speedup vs baseline: 1.3505x; 1.3505x over previous
//
#include <hip/hip_runtime.h>
#include <hip/hip_bf16.h>

#define NB 128
#define NT 1024
#define ND 512
#define NDA 576   // 512 (memory) + 64 (im2col window, 62 used + 2 zero pad)
#define NQ 1024
#define NA 128
#define NF 32
#define NK 31
#define CT4 64
#define NCH4 (NT / CT4)    // 16
#define ROWB 1152          // bytes per LDS sv row (576 bf16)

typedef __attribute__((ext_vector_type(8))) short short8;
typedef __attribute__((ext_vector_type(4))) float f32x4;
typedef __attribute__((ext_vector_type(4))) unsigned int u32x4;

__device__ __forceinline__ unsigned short f2bf(float f) {
  unsigned int u = __float_as_uint(f);
  u += 0x7fffu + ((u >> 16) & 1u);   // RNE; inputs are finite
  return (unsigned short)(u >> 16);
}
__device__ __forceinline__ unsigned int cvt_pk_bf16(float lo, float hi) {
  unsigned int r;
  asm("v_cvt_pk_bf16_f32 %0, %1, %2" : "=v"(r) : "v"(lo), "v"(hi));
  return r;
}
__device__ __forceinline__ float bf2f(unsigned short u) {
  return __uint_as_float((unsigned int)u << 16);
}
__device__ __forceinline__ float fast_tanh(float x) {
  const float e = __expf(2.f * x);
  return 1.f - 2.f / (e + 1.f);
}
// wt3 packed layout: per (col-tile ct = a>>4, kf = d>>5) a 1KB block,
// lane (lhi = (d>>3)&3, llo = a&15) holds 8 bf16 along k.
__device__ __forceinline__ int wt3_off(int a, int d) {
  return (((a >> 4) * 18 + (d >> 5)) << 9) + (((d >> 3) & 3) << 7) +
         ((a & 15) << 3) + (d & 7);
}

// ---------------------------------------------------------------------------
// Prep: pq partials (0..511), Wm^T -> wt3 (512..575), W2 = ck@Wloc (576..583)
// ---------------------------------------------------------------------------
__global__ __launch_bounds__(256) void lsa_prep(
    const float* __restrict__ query, const float* __restrict__ wq,
    const float* __restrict__ wm, const float* __restrict__ ck,
    const float* __restrict__ wloc,
    float* __restrict__ pq_part, unsigned short* __restrict__ wt3)
{
  const int bid = blockIdx.x;
  const int tid = threadIdx.x;
  if (bid < 512) {
    __shared__ float qs[256];
    __shared__ float red[256];
    const int b = bid >> 2;
    const int qg = bid & 3;
    qs[tid] = query[(size_t)b * NQ + qg * 256 + tid];
    __syncthreads();
    const int a = tid & 127;
    const int h = tid >> 7;
    const float* wqp = wq + (size_t)(qg * 256 + h * 128) * NA + a;
    float acc = 0.f;
#pragma unroll 8
    for (int qi = 0; qi < 128; ++qi)
      acc += qs[h * 128 + qi] * wqp[(size_t)qi * NA];
    red[tid] = acc;
    __syncthreads();
    if (h == 0) pq_part[((size_t)b * 4 + qg) * NA + a] = red[a] + red[128 + a];
  } else if (bid < 576) {
    const int blk = bid - 512;   // 0..63, 8 d-rows each
    for (int i = blk * 1024 + tid; i < blk * 1024 + 1024; i += 256) {
      const int dd = i >> 7, aa = i & 127;
      wt3[wt3_off(aa, dd)] = f2bf(wm[(size_t)dd * NA + aa]);
    }
  } else {
    // W2[w][a] = sum_f ck[k][ch][f]*wloc[f][a], w = 2k+ch; w=62,63 -> 0
    __shared__ float wl_s[NF * NA];
    __shared__ float ck_s[NK * 2 * NF];
    const int blk = bid - 576;   // 0..7
    for (int i = tid; i < NF * NA; i += 256) wl_s[i] = wloc[i];
    for (int i = tid; i < NK * 2 * NF; i += 256) ck_s[i] = ck[i];
    __syncthreads();
    const int a = tid & 127;
    const int h = tid >> 7;
#pragma unroll
    for (int wi = 0; wi < 4; ++wi) {
      const int w = blk * 8 + h * 4 + wi;
      float acc = 0.f;
      if (w < 62) {
        const int k = w >> 1, ch = w & 1;
#pragma unroll
        for (int f = 0; f < NF; ++f)
          acc += ck_s[k * 64 + ch * 32 + f] * wl_s[f * NA + a];
      }
      wt3[wt3_off(a, 512 + w)] = f2bf(acc);
    }
  }
}

// ---------------------------------------------------------------------------
// Main: one (b, 64-row chunk) per 512-thread block (8 waves); 2 blocks/CU.
// stage(2 halves) -> GEMM (8 waves x 16 cols x 4 row-tiles; B-frag reused
// over 64 rows) -> exp (no max: |score| <= sum|v| ~ 9) -> partial context.
// ---------------------------------------------------------------------------
__global__ __launch_bounds__(512, 4) void lsa_main(
    const float* __restrict__ memory, const int* __restrict__ msl,
    const float* __restrict__ prev, const float* __restrict__ cum,
    const float* __restrict__ pq_part, const float* __restrict__ v_g,
    const unsigned short* __restrict__ wt3,
    float* __restrict__ score_g, float* __restrict__ pl_g,
    float* __restrict__ pctx_g)
{
  const int bid = blockIdx.x;
  const int b = bid >> 4;
  const int ci = bid & 15;
  const int t0 = ci * CT4;
  const int len = msl[b];
  if (t0 >= len) return;                 // fully-masked chunk: comb skips it
  const int nvalid = min(CT4, len - t0);
  const int tid = threadIdx.x;
  const int wid = tid >> 6;              // 0..7
  const int lane = tid & 63;

  __shared__ __align__(16) unsigned short sv[CT4 * NDA];  // 72 KB
  __shared__ float score2[8][CT4];                        // 2 KB

  // ---- stage values -> bf16 LDS (swizzled), 2 halves of 32 rows ----
#pragma unroll
  for (int h = 0; h < 2; ++h) {
    const int r = h * 32 + (tid >> 4);   // row in chunk
    const int j = tid & 15;
    const float* src = memory + ((size_t)b * NT + (t0 + r)) * ND + j * 8;
    const f32x4 y0 = *(const f32x4*)(src);
    const f32x4 y1 = *(const f32x4*)(src + 4);
    const f32x4 y2 = *(const f32x4*)(src + 128);
    const f32x4 y3 = *(const f32x4*)(src + 132);
    const f32x4 y4 = *(const f32x4*)(src + 256);
    const f32x4 y5 = *(const f32x4*)(src + 260);
    const f32x4 y6 = *(const f32x4*)(src + 384);
    const f32x4 y7 = *(const f32x4*)(src + 388);
    char* svb = (char*)sv + r * ROWB;
    const int sw = (r & 7) << 4;
    u32x4 pk;
    pk[0] = cvt_pk_bf16(y0[0], y0[1]); pk[1] = cvt_pk_bf16(y0[2], y0[3]);
    pk[2] = cvt_pk_bf16(y1[0], y1[1]); pk[3] = cvt_pk_bf16(y1[2], y1[3]);
    *(u32x4*)(svb + ((j * 16) ^ sw)) = pk;
    pk[0] = cvt_pk_bf16(y2[0], y2[1]); pk[1] = cvt_pk_bf16(y2[2], y2[3]);
    pk[2] = cvt_pk_bf16(y3[0], y3[1]); pk[3] = cvt_pk_bf16(y3[2], y3[3]);
    *(u32x4*)(svb + ((j * 16 + 256) ^ sw)) = pk;
    pk[0] = cvt_pk_bf16(y4[0], y4[1]); pk[1] = cvt_pk_bf16(y4[2], y4[3]);
    pk[2] = cvt_pk_bf16(y5[0], y5[1]); pk[3] = cvt_pk_bf16(y5[2], y5[3]);
    *(u32x4*)(svb + ((j * 16 + 512) ^ sw)) = pk;
    pk[0] = cvt_pk_bf16(y6[0], y6[1]); pk[1] = cvt_pk_bf16(y6[2], y6[3]);
    pk[2] = cvt_pk_bf16(y7[0], y7[1]); pk[3] = cvt_pk_bf16(y7[2], y7[3]);
    *(u32x4*)(svb + ((j * 16 + 768) ^ sw)) = pk;
  }
  // ---- im2col window into cols 512..575 (8 w's per thread, 64 rows) ----
  {
    const int t = tid >> 3;              // 0..63
    const int w0 = (tid & 7) * 8;
    float xv[8];
#pragma unroll
    for (int i = 0; i < 8; ++i) {
      const int w = w0 + i;
      xv[i] = 0.f;
      if (w < 62) {
        const int t3 = t0 - 15 + (w >> 1) + t;
        if (t3 >= 0 && t3 < NT)
          xv[i] = (w & 1) ? cum[(size_t)b * NT + t3] : prev[(size_t)b * NT + t3];
      }
    }
    u32x4 pk;
    pk[0] = cvt_pk_bf16(xv[0], xv[1]); pk[1] = cvt_pk_bf16(xv[2], xv[3]);
    pk[2] = cvt_pk_bf16(xv[4], xv[5]); pk[3] = cvt_pk_bf16(xv[6], xv[7]);
    *(u32x4*)((char*)sv + t * ROWB + ((1024 + (tid & 7) * 16) ^ ((t & 7) << 4))) = pk;
  }
  __syncthreads();

  // ---- GEMM: 64(t) x 16 cols/wave x 576(k); B-frag reused x4 row-tiles ----
  const int llo = lane & 15, lhi = lane >> 4;
  const int c = wid * 16 + llo;          // this lane's output column
  float esc;
  {
    const unsigned short* bbase = wt3 + ((size_t)wid * 18) * 512 + lane * 8;
    const char* ab0 = (const char*)sv + llo * ROWB;          // rows 0..15
    const char* ab1 = ab0 + 16 * ROWB;                       // rows 16..31
    const char* ab2 = ab0 + 32 * ROWB;                       // rows 32..47
    const char* ab3 = ab0 + 48 * ROWB;                       // rows 48..63
    const int asw = (llo & 7) << 4;      // same for all 4 row tiles (16|8)
    const float* pp = pq_part + (size_t)b * 4 * NA;
    const float pqc = pp[c] + pp[NA + c] + pp[2 * NA + c] + pp[3 * NA + c];
    const float vc = v_g[c];
    f32x4 acc0 = {0.f, 0.f, 0.f, 0.f};
    f32x4 acc1 = {0.f, 0.f, 0.f, 0.f};
    f32x4 acc2 = {0.f, 0.f, 0.f, 0.f};
    f32x4 acc3 = {0.f, 0.f, 0.f, 0.f};
#pragma unroll
    for (int kf = 0; kf < 18; ++kf) {
      const short8 bq = *(const short8*)(bbase + kf * 512);
      const int bo = (kf * 64 + lhi * 16) ^ asw;
      const short8 a0 = *(const short8*)(ab0 + bo);
      const short8 a1 = *(const short8*)(ab1 + bo);
      const short8 a2 = *(const short8*)(ab2 + bo);
      const short8 a3 = *(const short8*)(ab3 + bo);
      acc0 = __builtin_amdgcn_mfma_f32_16x16x32_bf16(a0, bq, acc0, 0, 0, 0);
      acc1 = __builtin_amdgcn_mfma_f32_16x16x32_bf16(a1, bq, acc1, 0, 0, 0);
      acc2 = __builtin_amdgcn_mfma_f32_16x16x32_bf16(a2, bq, acc2, 0, 0, 0);
      acc3 = __builtin_amdgcn_mfma_f32_16x16x32_bf16(a3, bq, acc3, 0, 0, 0);
    }
#pragma unroll
    for (int mf = 0; mf < 4; ++mf) {
      const f32x4 av = (mf == 0) ? acc0 : (mf == 1) ? acc1 : (mf == 2) ? acc2 : acc3;
#pragma unroll
      for (int rg = 0; rg < 4; ++rg) {
        const int r = mf * 16 + lhi * 4 + rg;
        float e = fast_tanh(av[rg] + pqc) * vc;
        e += __shfl_xor(e, 1); e += __shfl_xor(e, 2);
        e += __shfl_xor(e, 4); e += __shfl_xor(e, 8);
        if (llo == 0) score2[wid][r] = e;
      }
    }
  }
  __syncthreads();

  // ---- exp weights (no max; |s| <= sum|v| ~ 9, f32-safe); t = lane ----
  {
    const int t = lane;
    float s = 0.f;
#pragma unroll
    for (int w = 0; w < 8; ++w) s += score2[w][t];
    if (wid == 0) score_g[(size_t)b * NT + t0 + t] = s;
    esc = (t < nvalid) ? __expf(s) : 0.f;
    float l = esc;
    l += __shfl_xor(l, 1);  l += __shfl_xor(l, 2);  l += __shfl_xor(l, 4);
    l += __shfl_xor(l, 8);  l += __shfl_xor(l, 16); l += __shfl_xor(l, 32);
    if (wid == 0 && lane == 0) pl_g[b * NCH4 + ci] = l;
  }

  // ---- partial context: wave covers 64 d's (8 groups of 8), 8 t-steps ----
  {
    const int gi = lane >> 3;            // 0..7
    const int sub = lane & 7;            // t-part
    const int g = wid * 8 + gi;          // d-group, d0 = 8g
    const char* svb = (const char*)sv;
    float a8[8];
#pragma unroll
    for (int i = 0; i < 8; ++i) a8[i] = 0.f;
#pragma unroll
    for (int tp = 0; tp < 8; ++tp) {
      const int t2 = tp * 8 + sub;
      const float ee = __shfl(esc, t2);  // lane t2 holds esc for row t2
      const short8 u =
          *(const short8*)(svb + t2 * ROWB + ((g * 16) ^ ((t2 & 7) << 4)));
#pragma unroll
      for (int i = 0; i < 8; ++i) a8[i] += ee * bf2f((unsigned short)u[i]);
    }
#pragma unroll
    for (int off = 1; off < 8; off <<= 1) {
#pragma unroll
      for (int i = 0; i < 8; ++i) a8[i] += __shfl_xor(a8[i], off);
    }
    if (sub == 0) {
      float* dst = pctx_g + ((size_t)(b * NCH4 + ci)) * ND + g * 8;
      const f32x4 lo = {a8[0], a8[1], a8[2], a8[3]};
      const f32x4 hi = {a8[4], a8[5], a8[6], a8[7]};
      *(f32x4*)dst = lo;
      *(f32x4*)(dst + 4) = hi;
    }
  }
}

// ---------------------------------------------------------------------------
// Combine: merge <=16 chunk partials per batch (no rescale: same exp scale).
// Grid NB*2: block (b, half) does 256 d's and 512 t's.
// ---------------------------------------------------------------------------
__global__ __launch_bounds__(256) void lsa_comb(
    const int* __restrict__ msl, const float* __restrict__ score_g,
    const float* __restrict__ cum, const float* __restrict__ pl_g,
    const float* __restrict__ pctx_g, float* __restrict__ out)
{
  const int bid = blockIdx.x;
  const int b = bid >> 1;
  const int hf = bid & 1;
  const int tid = threadIdx.x;
  const int len = msl[b];
  const int nck = (len + CT4 - 1) >> 6;   // 8..16
  __shared__ float MLsh;
  if (tid < 64) {
    float L = (tid < nck) ? pl_g[b * NCH4 + tid] : 0.f;
#pragma unroll
    for (int off = 1; off < 16; off <<= 1) L += __shfl_xor(L, off);
    if (tid == 0) MLsh = L;
  }
  __syncthreads();
  const float Linv = 1.f / MLsh;
  {
    const int d = hf * 256 + tid;
    const float* pb = pctx_g + (size_t)b * NCH4 * ND + d;
    float a0 = 0.f, a1 = 0.f, a2 = 0.f, a3 = 0.f;
    int i = 0;
    for (; i + 4 <= nck; i += 4) {
      a0 += pb[(size_t)(i + 0) * ND];
      a1 += pb[(size_t)(i + 1) * ND];
      a2 += pb[(size_t)(i + 2) * ND];
      a3 += pb[(size_t)(i + 3) * ND];
    }
    for (; i < nck; ++i) a0 += pb[(size_t)i * ND];
    out[(size_t)b * ND + d] = (a0 + a1 + a2 + a3) * Linv;
  }
  float* attn_o = out + (size_t)NB * ND;
  float* cum_o = attn_o + (size_t)NB * NT;
#pragma unroll
  for (int it = 0; it < 2; ++it) {
    const int t = hf * 512 + it * 256 + tid;
    float w = 0.f;
    if (t < len) w = __expf(score_g[(size_t)b * NT + t]) * Linv;
    attn_o[(size_t)b * NT + t] = w;
    cum_o[(size_t)b * NT + t] = w + cum[(size_t)b * NT + t];
  }
}

extern "C" void kernel_launch(void* const* d_in, const int* in_sizes, int n_in,
                              void* d_out, int out_size, void* d_ws, size_t ws_size,
                              hipStream_t stream) {
  const float* query  = (const float*)d_in[0];
  const float* prev   = (const float*)d_in[1];
  const float* cum    = (const float*)d_in[2];
  const float* memory = (const float*)d_in[3];
  const int*   msl    = (const int*)d_in[4];
  const float* wq     = (const float*)d_in[5];
  const float* wm     = (const float*)d_in[6];
  const float* ck     = (const float*)d_in[7];
  const float* wloc   = (const float*)d_in[8];
  const float* vv     = (const float*)d_in[9];
  float* out = (float*)d_out;

  // workspace layout (floats), ~5.5 MB
  float* ws = (float*)d_ws;
  float* score_g = ws;                        // 131072
  float* pl_g    = ws + 131072;               // 2048
  float* pctx_g  = ws + 133120;               // 128*16*512 = 1048576
  float* pq_part = ws + 1181696;              // 65536
  unsigned short* wt3 = (unsigned short*)(ws + 1247232);  // 73728 bf16

  lsa_prep<<<584, 256, 0, stream>>>(query, wq, wm, ck, wloc, pq_part, wt3);
  lsa_main<<<NB * NCH4, 512, 0, stream>>>(memory, msl, prev, cum, pq_part, vv,
                                          wt3, score_g, pl_g, pctx_g);
  lsa_comb<<<NB * 2, 256, 0, stream>>>(msl, score_g, cum, pl_g, pctx_g, out);
}